// Round 8
// baseline (155.141 us; speedup 1.0000x reference)
//
#include <hip/hip_runtime.h>

typedef unsigned long long u64;
typedef unsigned int u32;

#define MAXD 5
#define NTH  256
#define BSH  6
#define BN   64          // nodes per bin
#define CAPB 2816        // records per 64-node bin (mean 2048, +17 sigma)
#define EPB  4096        // edges per sortA block
#define MAXBIN 800
#define HEMPTY 0xFFFFFFFFu

// ---------------------------------------------------------------------------
// R19: R7 showed launch gaps + P-slab were NOT the cost (11->6 dispatches
// bought 4.8us): the time is in sortA's staging/binary-search and the
// latency-starved 391-block pulls. Fix:
//  (1) sortA: no LDS staging, no scan, no search. base[j]=atomicAdd(binCur,
//      hist[j]); records go DIRECTLY to binBuf as plain cached stores (L2
//      write-back aggregates; R3's failure was write-through, not scatter).
//      Depth-1 push (srcMask atomicOr, ~4K hits) fused in.
//  (2) pull1 deleted: depth-2 gathers read RAW NFg. Correct because a
//      srcbit pushed from u lands only on u's neighbors, which already
//      hold that bit at depth<=1 -> masked by ~Vis in the epilogue.
//      pull2's epilogue rebuilds f1/Vis/CNT from raw + per-block hash.
//  (3) 64-node bins -> 782 blocks/pull (12 waves/CU), 8-wide gather unroll
//      -> enough outstanding loads to hide L2 latency.
// No device atomics in pull gathers; frontier arrays read-only per pass
// (L2-resident, R5 lesson); all per-node state stores are bin-owned.
//
// Dispatches: memset(404KB) | sortA | pull2 | pull3 | pull4fin
// ws: NFg[N] (u64) binCur[1024] (u32) | Vis Fa Fb CNT [N] (u64) |
//     binBuf[NBIN*CAPB] (u32)
// ---------------------------------------------------------------------------

__device__ __forceinline__ void anchor_hash_build(
    const int* h, const int* t, const int* anchor, int A,
    u32* hsKey, u32* hsBit, int tid) {
    // call with tid<64 (wave 0): gather anchors, shfl dedup, hash insert
    int K = 2 * A;
    int a_ = (tid < K) ? anchor[(tid < A) ? tid : (tid - A)] : 0;
    int my = (tid < K) ? ((tid < A) ? h[a_] : t[a_]) : -1;
    bool uniq = (tid < K);
    for (int j = 0; j < 64; ++j) {
        int o = __shfl(my, j, 64);
        if (j < tid && o == my) uniq = false;
    }
    if (uniq) {
        u32 slot = ((u32)my * 2654435761u) >> 25;
        while (atomicCAS(&hsKey[slot], HEMPTY, (u32)my) != HEMPTY)
            slot = (slot + 1) & 127u;
        hsBit[slot] = (u32)tid;
    }
}

__device__ __forceinline__ u64 hash_lookup(const u32* hsKey, const u32* hsBit,
                                           u32 src) {
    u32 slot = (src * 2654435761u) >> 25;
    while (true) {
        u32 k = hsKey[slot];
        if (k == src) return 1ull << hsBit[slot];
        if (k == HEMPTY) return 0ull;
        slot = (slot + 1) & 127u;
    }
}

// bin-build: hist -> batched global cursor -> direct cached scatter; + d1 push
__global__ __launch_bounds__(NTH) void sortA(
    const int* __restrict__ h, const int* __restrict__ t, int E, int NBIN,
    const int* __restrict__ anchor, int A,
    u32* __restrict__ binCur, u32* __restrict__ binBuf, u64* __restrict__ NFg) {
    __shared__ u32 hist[MAXBIN], base[MAXBIN];
    __shared__ u32 hsKey[128], hsBit[128];
    int tid = threadIdx.x, b = blockIdx.x;
    for (int i = tid; i < NBIN; i += NTH) hist[i] = 0u;
    if (tid < 128) hsKey[tid] = HEMPTY;
    __syncthreads();
    if (tid < 64) anchor_hash_build(h, t, anchor, A, hsKey, hsBit, tid);

    int e0 = b * EPB;
    u32 eu[16], ev[16];
#pragma unroll
    for (int k = 0; k < 16; ++k) {
        int i = e0 + k * NTH + tid;
        if (i < E) {
            eu[k] = (u32)__builtin_nontemporal_load(h + i);
            ev[k] = (u32)__builtin_nontemporal_load(t + i);
            atomicAdd(&hist[ev[k] >> BSH], 1u);
            atomicAdd(&hist[eu[k] >> BSH], 1u);
        } else { eu[k] = HEMPTY; ev[k] = 0u; }
    }
    __syncthreads();   // hist + hash complete
    for (int j = tid; j < NBIN; j += NTH) {
        u32 c = hist[j];
        base[j] = c ? atomicAdd(&binCur[j], c) : 0u;
        hist[j] = 0u;                  // reuse as rank cursor
    }
    __syncthreads();
#pragma unroll
    for (int k = 0; k < 16; ++k) {
        if (eu[k] != HEMPTY) {
            u32 uu = eu[k], vv = ev[k];
            u32 b1 = vv >> BSH;
            u32 p1 = base[b1] + atomicAdd(&hist[b1], 1u);
            if (p1 < CAPB)
                binBuf[(size_t)b1 * CAPB + p1] = (uu << BSH) | (vv & (BN - 1));
            u32 b2 = uu >> BSH;
            u32 p2 = base[b2] + atomicAdd(&hist[b2], 1u);
            if (p2 < CAPB)
                binBuf[(size_t)b2 * CAPB + p2] = (vv << BSH) | (uu & (BN - 1));
            u64 mu = hash_lookup(hsKey, hsBit, uu);   // depth-1 push (~4K hits)
            if (mu) atomicOr(&NFg[vv], mu);
            u64 mv = hash_lookup(hsKey, hsBit, vv);
            if (mv) atomicOr(&NFg[uu], mv);
        }
    }
}

#define GATHER8(ra, rc, F)                                        \
    {                                                             \
        u64 f0 = F[ra.x >> BSH], f1 = F[ra.y >> BSH];             \
        u64 f2 = F[ra.z >> BSH], f3 = F[ra.w >> BSH];             \
        u64 f4 = F[rc.x >> BSH], f5 = F[rc.y >> BSH];             \
        u64 f6 = F[rc.z >> BSH], f7 = F[rc.w >> BSH];             \
        if (f0) atomicOr(&NF[ra.x & (BN - 1)], f0);               \
        if (f1) atomicOr(&NF[ra.y & (BN - 1)], f1);               \
        if (f2) atomicOr(&NF[ra.z & (BN - 1)], f2);               \
        if (f3) atomicOr(&NF[ra.w & (BN - 1)], f3);               \
        if (f4) atomicOr(&NF[rc.x & (BN - 1)], f4);               \
        if (f5) atomicOr(&NF[rc.y & (BN - 1)], f5);               \
        if (f6) atomicOr(&NF[rc.z & (BN - 1)], f6);               \
        if (f7) atomicOr(&NF[rc.w & (BN - 1)], f7);               \
    }

#define GATHER_LOOP(F)                                            \
    u32 cnt = min(binCur[bin], (u32)CAPB);                        \
    const uint4* rb4 = (const uint4*)(binBuf + (size_t)bin * CAPB); \
    const u32* rb = binBuf + (size_t)bin * CAPB;                  \
    u32 n4 = cnt >> 2;                                            \
    u32 i = (u32)tid;                                             \
    for (; i + NTH < n4; i += 2u * NTH) {                         \
        uint4 ra = rb4[i], rc = rb4[i + NTH];                     \
        GATHER8(ra, rc, F)                                        \
    }                                                             \
    for (; i < n4; i += NTH) {                                    \
        uint4 ra = rb4[i];                                        \
        u64 f0 = F[ra.x >> BSH], f1 = F[ra.y >> BSH];             \
        u64 f2 = F[ra.z >> BSH], f3 = F[ra.w >> BSH];             \
        if (f0) atomicOr(&NF[ra.x & (BN - 1)], f0);               \
        if (f1) atomicOr(&NF[ra.y & (BN - 1)], f1);               \
        if (f2) atomicOr(&NF[ra.z & (BN - 1)], f2);               \
        if (f3) atomicOr(&NF[ra.w & (BN - 1)], f3);               \
    }                                                             \
    for (u32 r = (n4 << 2) + (u32)tid; r < cnt; r += NTH) {       \
        u32 a0 = rb[r];                                           \
        u64 f0 = F[a0 >> BSH];                                    \
        if (f0) atomicOr(&NF[a0 & (BN - 1)], f0);                 \
    }

// depth-2 pull over RAW NFg; epilogue rebuilds f1/Vis/CNT from raw + hash
__global__ __launch_bounds__(NTH) void pull2(
    const u32* __restrict__ binBuf, const u32* __restrict__ binCur,
    const u64* __restrict__ NFg,
    const int* __restrict__ h, const int* __restrict__ t,
    const int* __restrict__ anchor, int A,
    u64* __restrict__ Fout, u64* __restrict__ Vis, u64* __restrict__ CNT,
    int N) {
    __shared__ u64 NF[BN];
    __shared__ u32 hsKey[128], hsBit[128];
    int tid = threadIdx.x, bin = blockIdx.x;
    if (tid < BN) NF[tid] = 0ull;
    if (tid < 128) hsKey[tid] = HEMPTY;
    __syncthreads();
    if (tid < 64) anchor_hash_build(h, t, anchor, A, hsKey, hsBit, tid);
    __syncthreads();
    GATHER_LOOP(NFg)
    __syncthreads();
    if (tid < BN) {
        int n = bin * BN + tid;
        if (n < N) {
            u64 raw = NFg[n];
            u64 srcbit = hash_lookup(hsKey, hsBit, (u32)n);
            u64 f1v = raw & ~srcbit;
            u64 vis1 = srcbit | f1v;
            u64 nw2 = NF[tid] & ~vis1;
            Fout[n] = nw2;
            Vis[n] = vis1 | nw2;
            CNT[n] = (srcbit ? 1ull : 0ull)
                   | ((u64)__popcll(f1v) << 8)
                   | ((u64)__popcll(nw2) << 16);
        }
    }
}

// depth-3 pull: gather Fin, bin-owned epilogue
__global__ __launch_bounds__(NTH) void pull3(
    const u32* __restrict__ binBuf, const u32* __restrict__ binCur,
    const u64* __restrict__ Fin, u64* __restrict__ Fout,
    u64* __restrict__ Vis, u64* __restrict__ CNT, int N) {
    __shared__ u64 NF[BN];
    int tid = threadIdx.x, bin = blockIdx.x;
    if (tid < BN) NF[tid] = 0ull;
    __syncthreads();
    GATHER_LOOP(Fin)
    __syncthreads();
    if (tid < BN) {
        int n = bin * BN + tid;
        if (n < N) {
            u64 vis = Vis[n];
            u64 nw = NF[tid] & ~vis;
            Fout[n] = nw;
            Vis[n] = vis | nw;
            CNT[n] += (u64)__popcll(nw) << 24;
        }
    }
}

// depth-4 pull + matmul epilogue (64 nodes x 4 float4 quads, D=16)
__global__ __launch_bounds__(NTH) void pull4fin(
    const u32* __restrict__ binBuf, const u32* __restrict__ binCur,
    const u64* __restrict__ Fin, const u64* __restrict__ Vis,
    const u64* __restrict__ CNT,
    const int* __restrict__ h, const int* __restrict__ t,
    const int* __restrict__ anchor, int A,
    const float* __restrict__ embed, float* __restrict__ out, int N) {
    __shared__ u64 NF[BN];
    __shared__ int nvs;
    int tid = threadIdx.x, bin = blockIdx.x;
    if (tid < BN) NF[tid] = 0ull;
    if (tid < 64) {   // wave 0: nvalid via shfl dedup
        int K = 2 * A;
        int a_ = (tid < K) ? anchor[(tid < A) ? tid : (tid - A)] : 0;
        int my = (tid < K) ? ((tid < A) ? h[a_] : t[a_]) : -1;
        bool uniq = (tid < K);
        for (int j = 0; j < 64; ++j) {
            int o = __shfl(my, j, 64);
            if (j < tid && o == my) uniq = false;
        }
        u64 mask = __ballot(uniq);
        if (tid == 0) nvs = (int)__popcll(mask);
    }
    __syncthreads();
    GATHER_LOOP(Fin)
    __syncthreads();
    int nl = tid >> 2, q = tid & 3;
    int n = bin * BN + nl;
    if (n >= N) return;
    int nv = nvs;
    u64 nw4 = NF[nl] & ~Vis[n];
    u64 c = CNT[n];
    float inv = 1.0f / (float)(nv > 0 ? nv : 1);
    float cd[MAXD + 1];
    int c4 = __popcll(nw4);
    int total = c4;
#pragma unroll
    for (int d = 0; d < 4; ++d) {
        int x = (int)((c >> (8 * d)) & 0xffull);
        total += x;
        cd[d] = (float)x;
    }
    cd[4] = (float)c4;
    cd[5] = (float)(nv - total);      // depth-5 + unreached

    const float4* e4 = (const float4*)embed;   // [6][4] float4 rows
    float4 acc = {0.f, 0.f, 0.f, 0.f};
#pragma unroll
    for (int d = 0; d <= MAXD; ++d) {
        float4 e = e4[d * 4 + q];
        acc.x += cd[d] * e.x; acc.y += cd[d] * e.y;
        acc.z += cd[d] * e.z; acc.w += cd[d] * e.w;
    }
    acc.x *= inv; acc.y *= inv; acc.z *= inv; acc.w *= inv;
    ((float4*)(out + (size_t)n * 16))[q] = acc;
}

extern "C" void kernel_launch(void* const* d_in, const int* in_sizes, int n_in,
                              void* d_out, int out_size, void* d_ws, size_t ws_size,
                              hipStream_t stream) {
    const int*   h      = (const int*)d_in[0];
    const int*   t      = (const int*)d_in[1];
    const int*   anchor = (const int*)d_in[2];
    const float* embed  = (const float*)d_in[4];
    float*       out    = (float*)d_out;

    int E = in_sizes[0];
    int A = in_sizes[2];                    // 32 anchor triples -> 64 sources
    int D = in_sizes[4] / (MAXD + 1);       // 16
    int N = out_size / D;                   // 50000
    int NBIN = (N + BN - 1) >> BSH;         // 782 bins = pull blocks
    int NBs  = (E + EPB - 1) / EPB;         // 196 sortA blocks
    (void)D;

    u64* NFg    = (u64*)d_ws;               // raw depth-1 masks
    u32* binCur = (u32*)(NFg + N);          // [1024]
    u64* Vis    = (u64*)(binCur + 1024);
    u64* Fa     = Vis + N;
    u64* Fb     = Fa + N;
    u64* CNT    = Fb + N;
    u32* binBuf = (u32*)(CNT + N);          // [NBIN][CAPB]

    // zero NFg + binCur in one shot (404 KB)
    hipMemsetAsync(NFg, 0, (size_t)N * 8 + 1024 * 4, stream);

    sortA<<<NBs, NTH, 0, stream>>>(h, t, E, NBIN, anchor, A,
                                   binCur, binBuf, NFg);
    pull2<<<NBIN, NTH, 0, stream>>>(binBuf, binCur, NFg, h, t, anchor, A,
                                    Fa, Vis, CNT, N);
    pull3<<<NBIN, NTH, 0, stream>>>(binBuf, binCur, Fa, Fb, Vis, CNT, N);
    pull4fin<<<NBIN, NTH, 0, stream>>>(binBuf, binCur, Fb, Vis, CNT,
                                       h, t, anchor, A, embed, out, N);
}